// Round 5
// baseline (290.837 us; speedup 1.0000x reference)
//
#include <hip/hip_runtime.h>

typedef __attribute__((ext_vector_type(8))) short bhalf8;
typedef __attribute__((ext_vector_type(4))) float floatx4;

#define ALPHA_LR 0.2f

__device__ __forceinline__ unsigned short f2bf(float f) {
  union { float f; unsigned int u; } v; v.f = f;
  unsigned int r = v.u + 0x7fffu + ((v.u >> 16) & 1u);
  return (unsigned short)(r >> 16);
}
__device__ __forceinline__ float bf2f(unsigned short u) {
  union { unsigned int u; float f; } v; v.u = ((unsigned int)u) << 16;
  return v.f;
}
// async global->LDS, 16B per lane; lds ptr must be wave-uniform (HW adds lane*16)
__device__ __forceinline__ void gld16(const void* g, void* l) {
  __builtin_amdgcn_global_load_lds((const __attribute__((address_space(1))) unsigned int*)g,
                                   (__attribute__((address_space(3))) unsigned int*)l,
                                   16, 0, 0);
}

// ---------------------------------------------------------------------------
// k0w: W [k][n] fp32 -> WT_hi/WT_lo bf16, k-tiled layout [ks=8][n=256][k'=32]
// ---------------------------------------------------------------------------
__global__ void k0w_split(const float* __restrict__ W,
                          unsigned short* __restrict__ WThi,
                          unsigned short* __restrict__ WTlo) {
  __shared__ float s[16][17];
  const int tx = threadIdx.x, ty = threadIdx.y;
  const int n0 = blockIdx.x * 16, k0 = blockIdx.y * 16;
  s[ty][tx] = W[(k0 + ty) * 256 + n0 + tx];
  __syncthreads();
  float v = s[tx][ty];  // = W[k0+tx][n0+ty]
  const int k = k0 + tx, n = n0 + ty;
  unsigned short hi = f2bf(v);
  unsigned short lo = f2bf(v - bf2f(hi));
  const int idx = (k >> 5) * 8192 + n * 32 + (k & 31);
  WThi[idx] = hi;
  WTlo[idx] = lo;
}

// ---------------------------------------------------------------------------
// k1: Wh = h @ W via split-bf16 MFMA (hi*hi + hi*lo + lo*hi), h split in-kernel.
// Writes WhPack bf16 [B][jt=64][f=256][j'=32] and s1/s2 (fp32 dots with a).
// ---------------------------------------------------------------------------
__global__ __launch_bounds__(512, 2) void k1_mfma(const float* __restrict__ h,
                                                  const unsigned short* __restrict__ Bhi_g,
                                                  const unsigned short* __restrict__ Blo_g,
                                                  const float* __restrict__ a_g,
                                                  unsigned short* __restrict__ WhPack,
                                                  float* __restrict__ s1,
                                                  float* __restrict__ s2) {
  __shared__ unsigned short Ah[64 * 264], Al[64 * 264];  // 33 KB each
  __shared__ unsigned short Bh[2][8192], Bl[2][8192];    // 16 KB per buffer
  __shared__ float s1red[64], s2red[64];
  const int t = threadIdx.x;
  const long r0 = (long)blockIdx.x * 64;
  const int wave = t >> 6, lane = t & 63;

  if (t < 64) { s1red[t] = 0.f; s2red[t] = 0.f; }

#pragma unroll
  for (int rep = 0; rep < 2; rep++) {
    const int off = wave * 1024 + rep * 512;
    gld16(Bhi_g + off + lane * 8, &Bh[0][off]);
    gld16(Blo_g + off + lane * 8, &Bl[0][off]);
  }

#pragma unroll
  for (int q = 0; q < 8; q++) {
    int idx = q * 512 + t;
    int row = idx >> 6, c4 = idx & 63;
    float4 x = *(const float4*)(h + (r0 + row) * 256 + c4 * 4);
    float xs[4] = {x.x, x.y, x.z, x.w};
    unsigned short hs[4], ls[4];
#pragma unroll
    for (int qq = 0; qq < 4; qq++) {
      hs[qq] = f2bf(xs[qq]);
      ls[qq] = f2bf(xs[qq] - bf2f(hs[qq]));
    }
    *(ushort4*)&Ah[row * 264 + c4 * 4] = (ushort4){hs[0], hs[1], hs[2], hs[3]};
    *(ushort4*)&Al[row * 264 + c4 * 4] = (ushort4){ls[0], ls[1], ls[2], ls[3]};
  }
  __syncthreads();

  const int wm = wave >> 2, wn = wave & 3;
  const int lhi = lane >> 4, llo = lane & 15;

  floatx4 acc[2][4];
#pragma unroll
  for (int mt = 0; mt < 2; mt++)
#pragma unroll
    for (int nt = 0; nt < 4; nt++) acc[mt][nt] = (floatx4){0.f, 0.f, 0.f, 0.f};

  for (int ks = 0; ks < 8; ks++) {
    const int cur = ks & 1, nxt = cur ^ 1, ksn = (ks + 1) & 7;
#pragma unroll
    for (int rep = 0; rep < 2; rep++) {
      const int off = wave * 1024 + rep * 512;
      gld16(Bhi_g + ksn * 8192 + off + lane * 8, &Bh[nxt][off]);
      gld16(Blo_g + ksn * 8192 + off + lane * 8, &Bl[nxt][off]);
    }

    const int k0 = ks * 32;
    bhalf8 ah[2], al[2], bh[4], bl[4];
#pragma unroll
    for (int mt = 0; mt < 2; mt++) {
      int ro = (wm * 32 + mt * 16 + llo) * 264 + k0 + lhi * 8;
      ah[mt] = *(const bhalf8*)&Ah[ro];
      al[mt] = *(const bhalf8*)&Al[ro];
    }
#pragma unroll
    for (int nt = 0; nt < 4; nt++) {
      int ro = (wn * 64 + nt * 16 + llo) * 32 + lhi * 8;
      bh[nt] = *(const bhalf8*)&Bh[cur][ro];
      bl[nt] = *(const bhalf8*)&Bl[cur][ro];
    }
#pragma unroll
    for (int mt = 0; mt < 2; mt++)
#pragma unroll
      for (int nt = 0; nt < 4; nt++) {
        acc[mt][nt] = __builtin_amdgcn_mfma_f32_16x16x32_bf16(ah[mt], bh[nt], acc[mt][nt], 0, 0, 0);
        acc[mt][nt] = __builtin_amdgcn_mfma_f32_16x16x32_bf16(ah[mt], bl[nt], acc[mt][nt], 0, 0, 0);
        acc[mt][nt] = __builtin_amdgcn_mfma_f32_16x16x32_bf16(al[mt], bh[nt], acc[mt][nt], 0, 0, 0);
      }
    __syncthreads();
  }

  float a1v[4], a2v[4];
#pragma unroll
  for (int nt = 0; nt < 4; nt++) {
    int f = wn * 64 + nt * 16 + llo;
    a1v[nt] = a_g[f];
    a2v[nt] = a_g[256 + f];
  }

  const int b = (int)(r0 >> 11);
  const int jt_base = (int)((r0 & 2047) >> 5);

#pragma unroll
  for (int mt = 0; mt < 2; mt++) {
    float p1[4], p2[4];
#pragma unroll
    for (int reg = 0; reg < 4; reg++) {
      p1[reg] = acc[mt][0][reg] * a1v[0] + acc[mt][1][reg] * a1v[1] +
                acc[mt][2][reg] * a1v[2] + acc[mt][3][reg] * a1v[3];
      p2[reg] = acc[mt][0][reg] * a2v[0] + acc[mt][1][reg] * a2v[1] +
                acc[mt][2][reg] * a2v[2] + acc[mt][3][reg] * a2v[3];
    }
#pragma unroll
    for (int off = 1; off < 16; off <<= 1) {
#pragma unroll
      for (int reg = 0; reg < 4; reg++) {
        p1[reg] += __shfl_xor(p1[reg], off);
        p2[reg] += __shfl_xor(p2[reg], off);
      }
    }
    if (llo == 0) {
#pragma unroll
      for (int reg = 0; reg < 4; reg++) {
        int il = wm * 32 + mt * 16 + lhi * 4 + reg;
        atomicAdd(&s1red[il], p1[reg]);
        atomicAdd(&s2red[il], p2[reg]);
      }
    }
#pragma unroll
    for (int nt = 0; nt < 4; nt++) {
      int f = wn * 64 + nt * 16 + llo;
      int jt = jt_base + wm;
      ushort4 pk = (ushort4){f2bf(acc[mt][nt][0]), f2bf(acc[mt][nt][1]),
                             f2bf(acc[mt][nt][2]), f2bf(acc[mt][nt][3])};
      *(ushort4*)&WhPack[((long)((b * 64 + jt) * 256 + f)) * 32 + mt * 16 + lhi * 4] = pk;
    }
  }

  __syncthreads();
  if (t < 64) {
    s1[r0 + t] = s1red[t];
    s2[r0 + t] = s2red[t];
  }
}

// ---------------------------------------------------------------------------
// K2 v2: per row r=(b,i): M = leaky(s1 + max_adj s2), l = sum of exps, then
// writes NORMALIZED attention row P[i][:] as bf16 (row-major, coalesced).
// The exps are computed here anyway for the denominator — storing them kills
// all exp work in k3.
// ---------------------------------------------------------------------------
__global__ __launch_bounds__(256) void k2_stats(const int* __restrict__ adj,
                                                const float* __restrict__ s1,
                                                const float* __restrict__ s2,
                                                unsigned short* __restrict__ Pn) {
  const int t = threadIdx.x;
  const long r = blockIdx.x;
  const int b = (int)(r >> 11);
  __shared__ float red[4];
  __shared__ int redi[4];

  const int4* arow = (const int4*)(adj + r * 2048);
  int4 a0 = arow[t * 2], a1 = arow[t * 2 + 1];
  unsigned int m8 = (unsigned)(a0.x > 0) | ((unsigned)(a0.y > 0) << 1) |
                    ((unsigned)(a0.z > 0) << 2) | ((unsigned)(a0.w > 0) << 3) |
                    ((unsigned)(a1.x > 0) << 4) | ((unsigned)(a1.y > 0) << 5) |
                    ((unsigned)(a1.z > 0) << 6) | ((unsigned)(a1.w > 0) << 7);

  int cnt = __popc(m8);
  for (int o = 32; o; o >>= 1) cnt += __shfl_xor(cnt, o);
  if ((t & 63) == 0) redi[t >> 6] = cnt;
  __syncthreads();
  int total = redi[0] + redi[1] + redi[2] + redi[3];
  if (total == 0) m8 = 0xFFu;  // degenerate row guard (prob ~2^-2048)

  const float4* s2p = (const float4*)(s2 + (long)b * 2048);
  float4 v0 = s2p[t * 2], v1 = s2p[t * 2 + 1];
  float sv[8] = {v0.x, v0.y, v0.z, v0.w, v1.x, v1.y, v1.z, v1.w};

  float mx = -INFINITY;
#pragma unroll
  for (int q = 0; q < 8; q++)
    if ((m8 >> q) & 1) mx = fmaxf(mx, sv[q]);
  for (int o = 32; o; o >>= 1) mx = fmaxf(mx, __shfl_xor(mx, o));
  if ((t & 63) == 0) red[t >> 6] = mx;
  __syncthreads();
  mx = fmaxf(fmaxf(red[0], red[1]), fmaxf(red[2], red[3]));

  const float s1i = s1[r];
  const float xm = s1i + mx;
  const float M = fmaxf(xm, ALPHA_LR * xm);

  // per-element exps (kept in registers), denominator
  float pq[8];
  float lsum = 0.f;
#pragma unroll
  for (int q = 0; q < 8; q++) {
    float x = s1i + sv[q];
    float le = fmaxf(x, ALPHA_LR * x);
    float e = ((m8 >> q) & 1) ? __expf(le - M) : 0.f;
    pq[q] = e;
    lsum += e;
  }
  for (int o = 32; o; o >>= 1) lsum += __shfl_xor(lsum, o);
  __syncthreads();  // red[] reuse
  if ((t & 63) == 0) red[t >> 6] = lsum;
  __syncthreads();
  lsum = red[0] + red[1] + red[2] + red[3];
  const float linv = 1.f / lsum;

  // normalized bf16 store: 8 contiguous shorts = 16 B per thread, 1KB/wave
  unsigned short pb[8];
#pragma unroll
  for (int q = 0; q < 8; q++) pb[q] = f2bf(pq[q] * linv);
  *(int4*)&Pn[r * 2048 + t * 8] = *(const int4*)pb;
}

// ---------------------------------------------------------------------------
// K3 v3: out = elu( Pn @ Wh ). Pure GEMM: A (Pn, row-major bf16) and
// B (WhPack, [jt][f][j'] tiled) fragments loaded straight from global into
// VGPRs, register double-buffered. NO LDS, NO barriers, NO exps.
// grid (4 fc, 16 ry, 8 b) x 256 thr; wave tile 32 rows x 64 f.
// ---------------------------------------------------------------------------
__global__ __launch_bounds__(256, 2) void k3_attn(const unsigned short* __restrict__ WhPack,
                                                  const unsigned short* __restrict__ Pn,
                                                  float* __restrict__ out) {
  const int t = threadIdx.x;
  const int fc = blockIdx.x;   // f-chunk (64 cols)
  const int ry = blockIdx.y;   // row-tile (128 rows)
  const int b = blockIdx.z;
  const int wave = t >> 6, lane = t & 63;
  const int lhi = lane >> 4, llo = lane & 15;
  const int rowbase = ry * 128 + wave * 32;  // this wave's 32 rows

  // B frag (jt, nt) at Bp + jt*8192 + nt*512 (dense 1KB per wave-load)
  const unsigned short* Bp = WhPack + ((long)b * 64) * 8192 + fc * 2048 + llo * 32 + lhi * 8;
  // A frag (jt, mt) at Ap + mt*16*2048 + jt*32 (16B/lane, 64B segments)
  const unsigned short* Ap = Pn + ((long)b * 2048 + rowbase + llo) * 2048 + lhi * 8;

  floatx4 acc[2][4];
#pragma unroll
  for (int mt = 0; mt < 2; mt++)
#pragma unroll
    for (int nt = 0; nt < 4; nt++) acc[mt][nt] = (floatx4){0.f, 0.f, 0.f, 0.f};

  bhalf8 A0[2], A1[2], B0[4], B1[4];

#define K3_LD(AB, BB, JT)                                                     \
  {                                                                           \
    _Pragma("unroll") for (int mt = 0; mt < 2; mt++)                          \
        AB[mt] = *(const bhalf8*)(Ap + mt * 32768 + (JT) * 32);               \
    _Pragma("unroll") for (int nt = 0; nt < 4; nt++)                          \
        BB[nt] = *(const bhalf8*)(Bp + (JT) * 8192 + nt * 512);               \
  }
#define K3_MM(AB, BB)                                                         \
  _Pragma("unroll") for (int mt = 0; mt < 2; mt++)                            \
      _Pragma("unroll") for (int nt = 0; nt < 4; nt++)                        \
          acc[mt][nt] = __builtin_amdgcn_mfma_f32_16x16x32_bf16(              \
              AB[mt], BB[nt], acc[mt][nt], 0, 0, 0);

  K3_LD(A0, B0, 0)
  for (int jt = 0; jt < 64; jt += 2) {
    K3_LD(A1, B1, jt + 1)
    K3_MM(A0, B0)
    const int jn = (jt + 2 < 64) ? jt + 2 : 63;
    K3_LD(A0, B0, jn)
    K3_MM(A1, B1)
  }
#undef K3_LD
#undef K3_MM

  // epilogue: C/D row = lhi*4+reg, col = llo; just ELU + store
#pragma unroll
  for (int mt = 0; mt < 2; mt++) {
#pragma unroll
    for (int nt = 0; nt < 4; nt++) {
#pragma unroll
      for (int reg = 0; reg < 4; reg++) {
        int row = rowbase + mt * 16 + lhi * 4 + reg;
        float v = acc[mt][nt][reg];
        v = v > 0.f ? v : expm1f(v);
        out[((long)b * 2048 + row) * 256 + fc * 64 + nt * 16 + llo] = v;
      }
    }
  }
}

// ---------------------------------------------------------------------------
extern "C" void kernel_launch(void* const* d_in, const int* in_sizes, int n_in,
                              void* d_out, int out_size, void* d_ws, size_t ws_size,
                              hipStream_t stream) {
  const float* h = (const float*)d_in[0];
  const int* adj = (const int*)d_in[1];
  const float* W = (const float*)d_in[2];
  const float* a = (const float*)d_in[3];
  float* out = (float*)d_out;

  char* ws = (char*)d_ws;
  unsigned short* WhPack = (unsigned short*)ws;            //  8,388,608 B
  unsigned short* Pn = (unsigned short*)(ws + 8388608);    // 67,108,864 B
  unsigned short* WThi = (unsigned short*)(ws + 75497472); //    131,072 B
  unsigned short* WTlo = (unsigned short*)(ws + 75628544); //    131,072 B
  float* s1 = (float*)(ws + 75759616);                     //     65,536 B
  float* s2 = (float*)(ws + 75825152);                     //     65,536 B

  hipLaunchKernelGGL(k0w_split, dim3(16, 16), dim3(16, 16), 0, stream, W, WThi, WTlo);
  hipLaunchKernelGGL(k1_mfma, dim3(256), dim3(512), 0, stream, h, WThi, WTlo, a,
                     WhPack, s1, s2);
  hipLaunchKernelGGL(k2_stats, dim3(16384), dim3(256), 0, stream, adj, s1, s2, Pn);
  hipLaunchKernelGGL(k3_attn, dim3(4, 16, 8), dim3(256), 0, stream, WhPack, Pn, out);
}

// Round 6
// 253.389 us; speedup vs baseline: 1.1478x; 1.1478x over previous
//
#include <hip/hip_runtime.h>

typedef __attribute__((ext_vector_type(8))) short bhalf8;
typedef __attribute__((ext_vector_type(4))) float floatx4;

#define ALPHA_LR 0.2f

__device__ __forceinline__ unsigned short f2bf(float f) {
  union { float f; unsigned int u; } v; v.f = f;
  unsigned int r = v.u + 0x7fffu + ((v.u >> 16) & 1u);
  return (unsigned short)(r >> 16);
}
__device__ __forceinline__ float bf2f(unsigned short u) {
  union { unsigned int u; float f; } v; v.u = ((unsigned int)u) << 16;
  return v.f;
}
// async global->LDS, 16B per lane; LDS dest is wave-uniform base + lane*16
__device__ __forceinline__ void gld16(const void* g, void* l) {
  __builtin_amdgcn_global_load_lds((const __attribute__((address_space(1))) unsigned int*)g,
                                   (__attribute__((address_space(3))) unsigned int*)l,
                                   16, 0, 0);
}

// ---------------------------------------------------------------------------
// k0w: W [k][n] fp32 -> WT_hi/WT_lo bf16, k-tiled layout [ks=8][n=256][k'=32].
// Also re-initializes s2maxEnc[8] (ws is re-poisoned before every call).
// ---------------------------------------------------------------------------
__global__ void k0w_split(const float* __restrict__ W,
                          unsigned short* __restrict__ WThi,
                          unsigned short* __restrict__ WTlo,
                          unsigned int* __restrict__ s2maxEnc) {
  __shared__ float s[16][17];
  const int tx = threadIdx.x, ty = threadIdx.y;
  if (blockIdx.x == 0 && blockIdx.y == 0 && ty == 0 && tx < 8) s2maxEnc[tx] = 0u;
  const int n0 = blockIdx.x * 16, k0 = blockIdx.y * 16;
  s[ty][tx] = W[(k0 + ty) * 256 + n0 + tx];
  __syncthreads();
  float v = s[tx][ty];  // = W[k0+tx][n0+ty]
  const int k = k0 + tx, n = n0 + ty;
  unsigned short hi = f2bf(v);
  unsigned short lo = f2bf(v - bf2f(hi));
  const int idx = (k >> 5) * 8192 + n * 32 + (k & 31);
  WThi[idx] = hi;
  WTlo[idx] = lo;
}

// ---------------------------------------------------------------------------
// k1: Wh = h @ W via split-bf16 MFMA (hi*hi + hi*lo + lo*hi), h split in-kernel.
// Writes WhPack bf16 [B][jt=64][f=256][j'=32], s1/s2 (fp32 dots with a), and
// per-batch encoded atomicMax of s2 (for the k3 softmax bound).
// ---------------------------------------------------------------------------
__global__ __launch_bounds__(512, 2) void k1_mfma(const float* __restrict__ h,
                                                  const unsigned short* __restrict__ Bhi_g,
                                                  const unsigned short* __restrict__ Blo_g,
                                                  const float* __restrict__ a_g,
                                                  unsigned short* __restrict__ WhPack,
                                                  float* __restrict__ s1,
                                                  float* __restrict__ s2,
                                                  unsigned int* __restrict__ s2maxEnc) {
  __shared__ unsigned short Ah[64 * 264], Al[64 * 264];  // 33 KB each
  __shared__ unsigned short Bh[2][8192], Bl[2][8192];    // 16 KB per buffer
  __shared__ float s1red[64], s2red[64];
  const int t = threadIdx.x;
  const long r0 = (long)blockIdx.x * 64;
  const int wave = t >> 6, lane = t & 63;

  if (t < 64) { s1red[t] = 0.f; s2red[t] = 0.f; }

#pragma unroll
  for (int rep = 0; rep < 2; rep++) {
    const int off = wave * 1024 + rep * 512;
    gld16(Bhi_g + off + lane * 8, &Bh[0][off]);
    gld16(Blo_g + off + lane * 8, &Bl[0][off]);
  }

#pragma unroll
  for (int q = 0; q < 8; q++) {
    int idx = q * 512 + t;
    int row = idx >> 6, c4 = idx & 63;
    float4 x = *(const float4*)(h + (r0 + row) * 256 + c4 * 4);
    float xs[4] = {x.x, x.y, x.z, x.w};
    unsigned short hs[4], ls[4];
#pragma unroll
    for (int qq = 0; qq < 4; qq++) {
      hs[qq] = f2bf(xs[qq]);
      ls[qq] = f2bf(xs[qq] - bf2f(hs[qq]));
    }
    *(ushort4*)&Ah[row * 264 + c4 * 4] = (ushort4){hs[0], hs[1], hs[2], hs[3]};
    *(ushort4*)&Al[row * 264 + c4 * 4] = (ushort4){ls[0], ls[1], ls[2], ls[3]};
  }
  __syncthreads();

  const int wm = wave >> 2, wn = wave & 3;
  const int lhi = lane >> 4, llo = lane & 15;

  floatx4 acc[2][4];
#pragma unroll
  for (int mt = 0; mt < 2; mt++)
#pragma unroll
    for (int nt = 0; nt < 4; nt++) acc[mt][nt] = (floatx4){0.f, 0.f, 0.f, 0.f};

  for (int ks = 0; ks < 8; ks++) {
    const int cur = ks & 1, nxt = cur ^ 1, ksn = (ks + 1) & 7;
#pragma unroll
    for (int rep = 0; rep < 2; rep++) {
      const int off = wave * 1024 + rep * 512;
      gld16(Bhi_g + ksn * 8192 + off + lane * 8, &Bh[nxt][off]);
      gld16(Blo_g + ksn * 8192 + off + lane * 8, &Bl[nxt][off]);
    }

    const int k0 = ks * 32;
    bhalf8 ah[2], al[2], bh[4], bl[4];
#pragma unroll
    for (int mt = 0; mt < 2; mt++) {
      int ro = (wm * 32 + mt * 16 + llo) * 264 + k0 + lhi * 8;
      ah[mt] = *(const bhalf8*)&Ah[ro];
      al[mt] = *(const bhalf8*)&Al[ro];
    }
#pragma unroll
    for (int nt = 0; nt < 4; nt++) {
      int ro = (wn * 64 + nt * 16 + llo) * 32 + lhi * 8;
      bh[nt] = *(const bhalf8*)&Bh[cur][ro];
      bl[nt] = *(const bhalf8*)&Bl[cur][ro];
    }
#pragma unroll
    for (int mt = 0; mt < 2; mt++)
#pragma unroll
      for (int nt = 0; nt < 4; nt++) {
        acc[mt][nt] = __builtin_amdgcn_mfma_f32_16x16x32_bf16(ah[mt], bh[nt], acc[mt][nt], 0, 0, 0);
        acc[mt][nt] = __builtin_amdgcn_mfma_f32_16x16x32_bf16(ah[mt], bl[nt], acc[mt][nt], 0, 0, 0);
        acc[mt][nt] = __builtin_amdgcn_mfma_f32_16x16x32_bf16(al[mt], bh[nt], acc[mt][nt], 0, 0, 0);
      }
    __syncthreads();
  }

  float a1v[4], a2v[4];
#pragma unroll
  for (int nt = 0; nt < 4; nt++) {
    int f = wn * 64 + nt * 16 + llo;
    a1v[nt] = a_g[f];
    a2v[nt] = a_g[256 + f];
  }

  const int b = (int)(r0 >> 11);
  const int jt_base = (int)((r0 & 2047) >> 5);

#pragma unroll
  for (int mt = 0; mt < 2; mt++) {
    float p1[4], p2[4];
#pragma unroll
    for (int reg = 0; reg < 4; reg++) {
      p1[reg] = acc[mt][0][reg] * a1v[0] + acc[mt][1][reg] * a1v[1] +
                acc[mt][2][reg] * a1v[2] + acc[mt][3][reg] * a1v[3];
      p2[reg] = acc[mt][0][reg] * a2v[0] + acc[mt][1][reg] * a2v[1] +
                acc[mt][2][reg] * a2v[2] + acc[mt][3][reg] * a2v[3];
    }
#pragma unroll
    for (int off = 1; off < 16; off <<= 1) {
#pragma unroll
      for (int reg = 0; reg < 4; reg++) {
        p1[reg] += __shfl_xor(p1[reg], off);
        p2[reg] += __shfl_xor(p2[reg], off);
      }
    }
    if (llo == 0) {
#pragma unroll
      for (int reg = 0; reg < 4; reg++) {
        int il = wm * 32 + mt * 16 + lhi * 4 + reg;
        atomicAdd(&s1red[il], p1[reg]);
        atomicAdd(&s2red[il], p2[reg]);
      }
    }
#pragma unroll
    for (int nt = 0; nt < 4; nt++) {
      int f = wn * 64 + nt * 16 + llo;
      int jt = jt_base + wm;
      ushort4 pk = (ushort4){f2bf(acc[mt][nt][0]), f2bf(acc[mt][nt][1]),
                             f2bf(acc[mt][nt][2]), f2bf(acc[mt][nt][3])};
      *(ushort4*)&WhPack[((long)((b * 64 + jt) * 256 + f)) * 32 + mt * 16 + lhi * 4] = pk;
    }
  }

  __syncthreads();
  if (t < 64) {
    s1[r0 + t] = s1red[t];
    s2[r0 + t] = s2red[t];
    // per-batch max(s2): 64-lane reduce + one encoded atomicMax per block
    float v = s2red[t];
#pragma unroll
    for (int o = 32; o; o >>= 1) v = fmaxf(v, __shfl_xor(v, o));
    if (t == 0) {
      unsigned int u = __float_as_uint(v);
      unsigned int key = (u & 0x80000000u) ? ~u : (u | 0x80000000u);
      atomicMax(s2maxEnc + b, key);
    }
  }
}

// ---------------------------------------------------------------------------
// K3 (fused stats): out = elu( softmax(mask(leaky(s1+s2))) @ Wh ).
// M_i = leaky(s1_i + max_batch s2) — a valid upper bound (softmax is
// shift-invariant; exps stay in [~e-20, 1]). Denominator accumulated in-loop
// by the P-computing threads, 16-lane reduced at the end. adj read directly
// (int2/thread/jt, 2-tile register prefetch). R3's single-barrier
// double-buffered structure. LDS ~45 KB.
// grid (64, 8) x 512 thr; block 32 rows x 256 f; wave tile 16 x 64.
// ---------------------------------------------------------------------------
__global__ __launch_bounds__(512, 4) void k3_attn(const unsigned short* __restrict__ WhPack,
                                                  const int* __restrict__ adj,
                                                  const float* __restrict__ s1g,
                                                  const float* __restrict__ s2g,
                                                  const unsigned int* __restrict__ s2maxEnc,
                                                  float* __restrict__ out) {
  const int t = threadIdx.x;
  const int i0 = blockIdx.x * 32;
  const int b = blockIdx.y;
  const long gr0 = (long)b * 2048 + i0;

  __shared__ float s2all[2048];            // 8 KB
  __shared__ unsigned short WhT[2][8192];  // [f=256][j'=32], 16 KB x2
  __shared__ unsigned short P[2][1280];    // [i=32][j' pad 40], 2.5 KB x2
  __shared__ float lvv[32];

  // stage s2 (whole batch row)
  ((float4*)s2all)[t] = ((const float4*)(s2g + (long)b * 2048))[t];

  const int wave = t >> 6, lane = t & 63;
  const int wm = wave >> 2, wn = wave & 3;
  const int lhi = lane >> 4, llo = lane & 15;
  const int i_p = t >> 4;        // P row (0..31)
  const int jl0 = (t & 15) * 2;  // P j-local base

  // per-P-thread row constants
  const float s1i = s1g[gr0 + i_p];
  const unsigned int ek = s2maxEnc[b];
  const float s2max = (ek & 0x80000000u) ? __uint_as_float(ek & 0x7fffffffu)
                                         : __uint_as_float(~ek);
  const float xm = s1i + s2max;
  const float Mi = fmaxf(xm, ALPHA_LR * xm);

  const int* aptr = adj + (gr0 + i_p) * 2048 + jl0;
  const unsigned short* tbase = WhPack + ((long)b * 64) * 8192;

  // prologue: async WhT tile0; adj tiles 0 and 1 into regs
#pragma unroll
  for (int rep = 0; rep < 2; rep++) {
    const int off = wave * 1024 + rep * 512;
    gld16(tbase + off + lane * 8, &WhT[0][off]);
  }
  int2 aj0 = *(const int2*)aptr;
  int2 aj1 = *(const int2*)(aptr + 32);

  __syncthreads();  // s2all visible (also drains WhT[0] vmem — harmless)

  float lsum;
  {  // P tile 0
    float x0 = s1i + s2all[jl0];
    float x1 = s1i + s2all[jl0 + 1];
    x0 = fmaxf(x0, ALPHA_LR * x0);
    x1 = fmaxf(x1, ALPHA_LR * x1);
    float e0 = (aj0.x > 0) ? __expf(x0 - Mi) : 0.f;
    float e1 = (aj0.y > 0) ? __expf(x1 - Mi) : 0.f;
    lsum = e0 + e1;
    *(unsigned int*)&P[0][i_p * 40 + jl0] =
        (unsigned)f2bf(e0) | ((unsigned)f2bf(e1) << 16);
  }
  __syncthreads();  // P[0] + WhT[0] ready

  floatx4 acc[4];
#pragma unroll
  for (int nt = 0; nt < 4; nt++) acc[nt] = (floatx4){0.f, 0.f, 0.f, 0.f};

  for (int jt = 0; jt < 64; jt++) {
    const int cur = jt & 1, nxt = cur ^ 1;
    if (jt < 63) {
      const int jtn = jt + 1;
#pragma unroll
      for (int rep = 0; rep < 2; rep++) {
        const int off = wave * 1024 + rep * 512;
        gld16(tbase + jtn * 8192 + off + lane * 8, &WhT[nxt][off]);
      }
      const int2 ajc = aj1;
      const int jpf = (jt + 2 < 64) ? jt + 2 : 63;
      aj1 = *(const int2*)(aptr + jpf * 32);  // prefetch
      float x0 = s1i + s2all[jtn * 32 + jl0];
      float x1 = s1i + s2all[jtn * 32 + jl0 + 1];
      x0 = fmaxf(x0, ALPHA_LR * x0);
      x1 = fmaxf(x1, ALPHA_LR * x1);
      float e0 = (ajc.x > 0) ? __expf(x0 - Mi) : 0.f;
      float e1 = (ajc.y > 0) ? __expf(x1 - Mi) : 0.f;
      lsum += e0 + e1;
      *(unsigned int*)&P[nxt][i_p * 40 + jl0] =
          (unsigned)f2bf(e0) | ((unsigned)f2bf(e1) << 16);
    }
    // frags from current buffers + MFMA
    bhalf8 af = *(const bhalf8*)&P[cur][(wm * 16 + llo) * 40 + lhi * 8];
    bhalf8 bf[4];
#pragma unroll
    for (int nt = 0; nt < 4; nt++)
      bf[nt] = *(const bhalf8*)&WhT[cur][(wn * 64 + nt * 16 + llo) * 32 + lhi * 8];
#pragma unroll
    for (int nt = 0; nt < 4; nt++)
      acc[nt] = __builtin_amdgcn_mfma_f32_16x16x32_bf16(af, bf[nt], acc[nt], 0, 0, 0);
    __syncthreads();
  }

  // denominator: reduce lsum across the 16 lanes sharing row i_p
  lsum += __shfl_xor(lsum, 1);
  lsum += __shfl_xor(lsum, 2);
  lsum += __shfl_xor(lsum, 4);
  lsum += __shfl_xor(lsum, 8);
  if ((t & 15) == 0) lvv[i_p] = 1.f / fmaxf(lsum, 1e-35f);
  __syncthreads();

  // epilogue: normalize, ELU, store. C/D: row = lhi*4+reg, col = llo
#pragma unroll
  for (int nt = 0; nt < 4; nt++) {
#pragma unroll
    for (int reg = 0; reg < 4; reg++) {
      int il = wm * 16 + lhi * 4 + reg;
      int f = wn * 64 + nt * 16 + llo;
      float v = acc[nt][reg] * lvv[il];
      v = v > 0.f ? v : expm1f(v);
      out[(gr0 + il) * 256 + f] = v;
    }
  }
}

// ---------------------------------------------------------------------------
extern "C" void kernel_launch(void* const* d_in, const int* in_sizes, int n_in,
                              void* d_out, int out_size, void* d_ws, size_t ws_size,
                              hipStream_t stream) {
  const float* h = (const float*)d_in[0];
  const int* adj = (const int*)d_in[1];
  const float* W = (const float*)d_in[2];
  const float* a = (const float*)d_in[3];
  float* out = (float*)d_out;

  char* ws = (char*)d_ws;
  unsigned short* WhPack = (unsigned short*)ws;            //  8,388,608 B
  unsigned short* WThi = (unsigned short*)(ws + 8388608);  //    131,072 B
  unsigned short* WTlo = (unsigned short*)(ws + 8519680);  //    131,072 B
  float* s1 = (float*)(ws + 8650752);                      //     65,536 B
  float* s2 = (float*)(ws + 8716288);                      //     65,536 B
  unsigned int* s2maxEnc = (unsigned int*)(ws + 8781824);  //         32 B

  hipLaunchKernelGGL(k0w_split, dim3(16, 16), dim3(16, 16), 0, stream, W, WThi, WTlo, s2maxEnc);
  hipLaunchKernelGGL(k1_mfma, dim3(256), dim3(512), 0, stream, h, WThi, WTlo, a,
                     WhPack, s1, s2, s2maxEnc);
  hipLaunchKernelGGL(k3_attn, dim3(64, 8), dim3(512), 0, stream, WhPack, adj,
                     s1, s2, s2maxEnc, out);
}